// Round 15
// baseline (84.169 us; speedup 1.0000x reference)
//
#include <hip/hip_runtime.h>
#include <hip/hip_bf16.h>

#define NSEQ 4096
#define FT 256
#define BK 64
#define BKB 128
#define NTB (NSEQ / BKB)  // 32

typedef __attribute__((ext_vector_type(8))) short bf16x8;
typedef __attribute__((ext_vector_type(4))) float f32x4;

__device__ __forceinline__ ushort f2bf(float f) {
  __hip_bfloat16 h = __float2bfloat16(f);
  return *reinterpret_cast<const ushort*>(&h);
}

// XOR swizzle of 16B granules within a 128B row.
__device__ __forceinline__ int swz(int row, int byteInRow) {
  return row * 128 + (byteInRow ^ ((row & 7) << 4));
}

__device__ __forceinline__ void mma_step(const char* lAp, const char* lBp,
                                         int lane, int wm, int wn,
                                         f32x4 acc[2][4]) {
  const int r16 = lane & 15;
  const int g16 = (lane >> 4) * 16;
#pragma unroll
  for (int kk = 0; kk < 2; ++kk) {
    const int kb = kk * 64 + g16;
    bf16x8 a[2], b[4];
#pragma unroll
    for (int mi = 0; mi < 2; ++mi) {
      const int row = wm * 32 + mi * 16 + r16;
      a[mi] = *reinterpret_cast<const bf16x8*>(lAp + swz(row, kb));
    }
#pragma unroll
    for (int ni = 0; ni < 4; ++ni) {
      const int row = wn * 64 + ni * 16 + r16;
      b[ni] = *reinterpret_cast<const bf16x8*>(lBp + swz(row, kb));
    }
#pragma unroll
    for (int mi = 0; mi < 2; ++mi)
#pragma unroll
      for (int ni = 0; ni < 4; ++ni)
        acc[mi][ni] = __builtin_amdgcn_mfma_f32_16x16x32_bf16(a[mi], b[ni],
                                                             acc[mi][ni], 0, 0, 0);
  }
}

// ---------------- Kernel A: hT[b][o][n] = (seq @ W^T + b) bf16 ----------------
// Epilogue: LDS transpose -> coalesced 16B hT stores.
__global__ __launch_bounds__(512) void linear_kernel(
    const float* __restrict__ seq, const float* __restrict__ W,
    const float* __restrict__ bias, ushort* __restrict__ hT) {
  __shared__ __align__(16) ushort lA[2][64 * 64];
  __shared__ __align__(16) ushort lB[2][256 * 64];

  const int tid = threadIdx.x;
  const int lane = tid & 63;
  const int wid = tid >> 6;
  const int wm = wid >> 2, wn = wid & 3;
  const int m0 = blockIdx.x * 64;

  const int ar = tid >> 4, ac = tid & 15;

  f32x4 rA[2];
  f32x4 rB[8];

  auto gload = [&](int t) {
    const int k0 = t * BK;
#pragma unroll
    for (int p = 0; p < 2; ++p)
      rA[p] = *reinterpret_cast<const f32x4*>(
          seq + (size_t)(m0 + ar + p * 32) * FT + k0 + ac * 4);
#pragma unroll
    for (int p = 0; p < 8; ++p)
      rB[p] = *reinterpret_cast<const f32x4*>(
          W + (size_t)(ar + p * 32) * FT + k0 + ac * 4);
  };
  auto lwrite = [&](int buf) {
    char* lAp = (char*)lA[buf];
    char* lBp = (char*)lB[buf];
#pragma unroll
    for (int p = 0; p < 2; ++p) {
      ushort4 u = make_ushort4(f2bf(rA[p][0]), f2bf(rA[p][1]), f2bf(rA[p][2]), f2bf(rA[p][3]));
      *reinterpret_cast<ushort4*>(lAp + swz(ar + p * 32, ac * 8)) = u;
    }
#pragma unroll
    for (int p = 0; p < 8; ++p) {
      ushort4 u = make_ushort4(f2bf(rB[p][0]), f2bf(rB[p][1]), f2bf(rB[p][2]), f2bf(rB[p][3]));
      *reinterpret_cast<ushort4*>(lBp + swz(ar + p * 32, ac * 8)) = u;
    }
  };

  f32x4 acc[2][4];
  const f32x4 zero = {0.f, 0.f, 0.f, 0.f};
#pragma unroll
  for (int mi = 0; mi < 2; ++mi)
#pragma unroll
    for (int ni = 0; ni < 4; ++ni) acc[mi][ni] = zero;

  gload(0);
  lwrite(0);
  const int NTA = FT / BK;  // 4
  for (int t = 0; t < NTA; ++t) {
    const int cur = t & 1;
    __syncthreads();
    if (t + 1 < NTA) gload(t + 1);
    mma_step((const char*)lA[cur], (const char*)lB[cur], lane, wm, wn, acc);
    if (t + 1 < NTA) lwrite(cur ^ 1);
  }

  // Epilogue: +bias, bf16, transpose via LDS overlay, coalesced stores.
  __syncthreads();
  ushort* lT = (ushort*)&lB[0][0];  // [256][72] ushort = 36 KB overlay
  const int TP = 72;
#pragma unroll
  for (int mi = 0; mi < 2; ++mi) {
    const int rbase = wm * 32 + mi * 16 + ((lane >> 4) << 2);
#pragma unroll
    for (int ni = 0; ni < 4; ++ni) {
      const int o = wn * 64 + ni * 16 + (lane & 15);
      const float bo = bias[o];
      ushort4 u;
      u.x = f2bf(acc[mi][ni][0] + bo);
      u.y = f2bf(acc[mi][ni][1] + bo);
      u.z = f2bf(acc[mi][ni][2] + bo);
      u.w = f2bf(acc[mi][ni][3] + bo);
      *reinterpret_cast<ushort4*>(&lT[o * TP + rbase]) = u;
    }
  }
  __syncthreads();
  const int batch = (blockIdx.x * 64) >> 12;   // blocks never straddle a batch
  const int n0 = (blockIdx.x * 64) & (NSEQ - 1);
  const int o = tid >> 1, hf = tid & 1;        // 256 o-rows x 2 halves
  ushort* dst = hT + ((size_t)(batch * FT + o)) * NSEQ + n0 + hf * 32;
#pragma unroll
  for (int k = 0; k < 4; ++k) {  // 4 x 16B contiguous per thread
    uint4 v = *reinterpret_cast<const uint4*>(&lT[o * TP + hf * 32 + k * 8]);
    *reinterpret_cast<uint4*>(dst + k * 8) = v;
  }
}

// ---------------- Kernel B (R9 structure): out = PReLU(adj @ h), BK=128 ----------------
__global__ __launch_bounds__(512) void bmm_prelu_kernel(
    const float* __restrict__ adj, const ushort* __restrict__ hT,
    const float* __restrict__ alphaP, float* __restrict__ out) {
  __shared__ __align__(16) char smem[2 * 65536 + 2 * 16384];  // lB[2] | lA[2]

  const int tid = threadIdx.x;
  const int lane = tid & 63;
  const int wid = tid >> 6;
  const int wm = wid >> 2, wn = wid & 3;

  const int bid = blockIdx.x;
  const int sbid = (bid & 7) * 32 + (bid >> 3);
  const int batch = sbid >> 6;
  const int m0 = (sbid & 63) * 64;

  const float* adjB = adj + (size_t)batch * NSEQ * NSEQ + (size_t)m0 * NSEQ;
  const ushort* hTB = hT + (size_t)batch * FT * NSEQ;

  auto lB = [&](int i) -> char* { return smem + i * 65536; };
  auto lA = [&](int i) -> char* { return smem + 131072 + i * 16384; };

  const int arow = tid >> 3, ac = tid & 7;
  const int bro = (lane >> 4);
  const int bhalf = (lane >> 3) & 1;
  f32x4 rS[4];

  f32x4 acc[2][4];
  const f32x4 zero = {0.f, 0.f, 0.f, 0.f};
#pragma unroll
  for (int mi = 0; mi < 2; ++mi)
#pragma unroll
    for (int ni = 0; ni < 4; ++ni) acc[mi][ni] = zero;

  auto issueA = [&](int t) {
    const int k0 = t * BKB;
#pragma unroll
    for (int q = 0; q < 4; ++q)
      rS[q] = *reinterpret_cast<const f32x4*>(
          adjB + (size_t)arow * NSEQ + k0 + ac * 16 + q * 4);
  };
  auto issueB = [&](int t, int ib) {
    const int k0 = t * BKB;
#pragma unroll
    for (int p = 0; p < 8; ++p) {
      const int grow = wid * 32 + p * 4 + bro;
      const int gsrc = (lane & 7) ^ (((p & 1) * 4 + bro) & 7);
      const ushort* gp = hTB + (size_t)grow * NSEQ + k0 + bhalf * 64 + gsrc * 8;
      char* lp = lB(ib) + wid * 8192 + p * 1024;
      __builtin_amdgcn_global_load_lds(
          (const __attribute__((address_space(1))) void*)gp,
          (__attribute__((address_space(3))) void*)lp, 16, 0, 0);
    }
  };
  auto writeA = [&](int ia) {
    char* lAp = lA(ia);
    const int half = ac >> 2;
#pragma unroll
    for (int q = 0; q < 4; ++q) {
      ushort4 u = make_ushort4(f2bf(rS[q][0]), f2bf(rS[q][1]),
                               f2bf(rS[q][2]), f2bf(rS[q][3]));
      const int gih = (((ac & 3) * 2 + (q >> 1)) ^ (arow & 7));
      *reinterpret_cast<ushort4*>(lAp + arow * 256 + half * 128 + gih * 16 +
                                  (q & 1) * 8) = u;
    }
  };
  auto mma32 = [&](const char* lAp, const char* lBp) {
    const int r16 = lane & 15;
    const int sub = lane >> 4;
#pragma unroll
    for (int kk = 0; kk < 4; ++kk) {
      const int half = kk >> 1;
      const int gih = (((kk & 1) * 4 + sub) ^ (r16 & 7));
      const int bofs = half * 128 + gih * 16;
      bf16x8 a[2], b[4];
#pragma unroll
      for (int mi = 0; mi < 2; ++mi) {
        const int row = wm * 32 + mi * 16 + r16;
        a[mi] = *reinterpret_cast<const bf16x8*>(lAp + row * 256 + bofs);
      }
#pragma unroll
      for (int ni = 0; ni < 4; ++ni) {
        const int row = wn * 64 + ni * 16 + r16;
        b[ni] = *reinterpret_cast<const bf16x8*>(lBp + row * 256 + bofs);
      }
#pragma unroll
      for (int mi = 0; mi < 2; ++mi)
#pragma unroll
        for (int ni = 0; ni < 4; ++ni)
          acc[mi][ni] = __builtin_amdgcn_mfma_f32_16x16x32_bf16(
              a[mi], b[ni], acc[mi][ni], 0, 0, 0);
    }
  };

  issueA(0);
  __builtin_amdgcn_sched_barrier(0);
  issueB(0, 0);
  __builtin_amdgcn_sched_barrier(0);
  asm volatile("s_waitcnt vmcnt(8)" ::: "memory");
  __builtin_amdgcn_sched_barrier(0);
  writeA(0);
  asm volatile("s_waitcnt vmcnt(0) lgkmcnt(0)" ::: "memory");
  __builtin_amdgcn_s_barrier();
  __builtin_amdgcn_sched_barrier(0);

  auto body = [&](int t, int cur) {
    issueA(t + 1);
    __builtin_amdgcn_sched_barrier(0);
    issueB(t + 1, cur ^ 1);
    __builtin_amdgcn_sched_barrier(0);
    __builtin_amdgcn_s_setprio(1);
    mma32(lA(cur), lB(cur));
    __builtin_amdgcn_s_setprio(0);
    asm volatile("s_waitcnt vmcnt(8)" ::: "memory");
    __builtin_amdgcn_sched_barrier(0);
    writeA(cur ^ 1);
    asm volatile("s_waitcnt vmcnt(0) lgkmcnt(0)" ::: "memory");
    __builtin_amdgcn_s_barrier();
    __builtin_amdgcn_sched_barrier(0);
  };

  for (int j = 0; j < 15; ++j) {
    body(2 * j, 0);
    body(2 * j + 1, 1);
  }
  body(30, 0);
  __builtin_amdgcn_s_setprio(1);
  mma32(lA(1), lB(1));
  __builtin_amdgcn_s_setprio(0);

  const float alpha = *alphaP;
  __syncthreads();
  float* lo = (float*)smem;
  const int PITCH = 264;
#pragma unroll
  for (int mi = 0; mi < 2; ++mi) {
    const int rbase = wm * 32 + mi * 16 + ((lane >> 4) << 2);
#pragma unroll
    for (int ni = 0; ni < 4; ++ni) {
      const int o = wn * 64 + ni * 16 + (lane & 15);
#pragma unroll
      for (int j = 0; j < 4; ++j) {
        float v = acc[mi][ni][j];
        v = v > 0.f ? v : alpha * v;
        lo[(rbase + j) * PITCH + o] = v;
      }
    }
  }
  __syncthreads();
  float* outB = out + ((size_t)batch * NSEQ + m0) * FT;
  const int r = tid >> 3, c8 = tid & 7;
#pragma unroll
  for (int k = 0; k < 8; ++k) {
    const int g = c8 + k * 8;
    f32x4 v = *reinterpret_cast<const f32x4*>(lo + r * PITCH + g * 4);
    __builtin_nontemporal_store(v, reinterpret_cast<f32x4*>(outB + (size_t)r * FT + g * 4));
  }
}

extern "C" void kernel_launch(void* const* d_in, const int* in_sizes, int n_in,
                              void* d_out, int out_size, void* d_ws, size_t ws_size,
                              hipStream_t stream) {
  const float* seq = (const float*)d_in[0];
  const float* adj = (const float*)d_in[1];
  const float* W = (const float*)d_in[2];
  const float* bias = (const float*)d_in[3];
  const float* alpha = (const float*)d_in[4];
  float* out = (float*)d_out;
  ushort* hT = (ushort*)d_ws;  // [4][256][4096] bf16 = 8 MB

  linear_kernel<<<256, 512, 0, stream>>>(seq, W, bias, hT);
  bmm_prelu_kernel<<<256, 512, 0, stream>>>(adj, hT, alpha, out);
}

// Round 16
// 83.341 us; speedup vs baseline: 1.0099x; 1.0099x over previous
//
#include <hip/hip_runtime.h>
#include <hip/hip_bf16.h>

#define NSEQ 4096
#define FT 256
#define BKB 128

typedef __attribute__((ext_vector_type(8))) short bf16x8;
typedef __attribute__((ext_vector_type(4))) float f32x4;

__device__ __forceinline__ ushort f2bf(float f) {
  __hip_bfloat16 h = __float2bfloat16(f);
  return *reinterpret_cast<const ushort*>(&h);
}

// XOR swizzle of 16B granules within a 128B row.
__device__ __forceinline__ int swz(int row, int byteInRow) {
  return row * 128 + (byteInRow ^ ((row & 7) << 4));
}

// ---------------- Kernel A: seqT[b][f][n] = bf16(seq[b][n][f]) ----------------
// Pure transpose-cast (no GEMM): 26 MB traffic ~4-5 us. Same [256][4096]
// bf16 layout role hT had, so kernel B's staging is unchanged.
__global__ __launch_bounds__(512) void transpose_cast_kernel(
    const float* __restrict__ seq, ushort* __restrict__ seqT) {
  __shared__ __align__(16) ushort lT[256 * 72];  // 36 KB

  const int tid = threadIdx.x;
  const int batch = blockIdx.x >> 6;
  const int n0 = (blockIdx.x & 63) * 64;
  const float* src = seq + ((size_t)batch * NSEQ + n0) * FT;

  const int ar = tid >> 3, ac = tid & 7;  // row 0..63, chunk 0..7
#pragma unroll
  for (int p = 0; p < 8; ++p) {
    const int fb = (ac + p * 8) * 4;
    f32x4 v = *reinterpret_cast<const f32x4*>(src + (size_t)ar * FT + fb);
#pragma unroll
    for (int e = 0; e < 4; ++e) lT[(fb + e) * 72 + ar] = f2bf(v[e]);
  }
  __syncthreads();
  const int f = tid >> 1, hf = tid & 1;
  ushort* dst = seqT + ((size_t)(batch * FT + f)) * NSEQ + n0 + hf * 32;
#pragma unroll
  for (int k = 0; k < 4; ++k) {
    uint4 v = *reinterpret_cast<const uint4*>(&lT[f * 72 + hf * 32 + k * 8]);
    *reinterpret_cast<uint4*>(dst + k * 8) = v;
  }
}

// ---------------- Kernel B: out = PReLU((adj @ seq) @ W^T + b*rowsum(adj)) --------------
// Main loop: R13/R9-verified schedule byte-identical (B operand = seqT).
// Epilogue: tmp(bf16,LDS) @ W^T in 4 chunks + bias*rowsum + PReLU + store.
__global__ __launch_bounds__(512) void bmm_prelu_kernel(
    const float* __restrict__ adj, const ushort* __restrict__ seqT,
    const float* __restrict__ W, const float* __restrict__ bias,
    const float* __restrict__ alphaP, float* __restrict__ out) {
  __shared__ __align__(16) char smem[2 * 65536 + 2 * 16384];  // lB[2] | lA[2]

  const int tid = threadIdx.x;
  const int lane = tid & 63;
  const int wid = tid >> 6;
  const int wm = wid >> 2, wn = wid & 3;

  const int bid = blockIdx.x;
  const int sbid = (bid & 7) * 32 + (bid >> 3);
  const int batch = sbid >> 6;
  const int m0 = (sbid & 63) * 64;

  const float* adjB = adj + (size_t)batch * NSEQ * NSEQ + (size_t)m0 * NSEQ;
  const ushort* hTB = seqT + (size_t)batch * FT * NSEQ;

  auto lB = [&](int i) -> char* { return smem + i * 65536; };
  auto lA = [&](int i) -> char* { return smem + 131072 + i * 16384; };

  const int arow = tid >> 3, ac = tid & 7;
  const int bro = (lane >> 4);
  const int bhalf = (lane >> 3) & 1;
  f32x4 rS[4];
  float rsum = 0.f;  // per-thread partial rowsum of adj row `arow`

  f32x4 acc[2][4];
  const f32x4 zero = {0.f, 0.f, 0.f, 0.f};
#pragma unroll
  for (int mi = 0; mi < 2; ++mi)
#pragma unroll
    for (int ni = 0; ni < 4; ++ni) acc[mi][ni] = zero;

  auto issueA = [&](int t) {
    const int k0 = t * BKB;
#pragma unroll
    for (int q = 0; q < 4; ++q)
      rS[q] = *reinterpret_cast<const f32x4*>(
          adjB + (size_t)arow * NSEQ + k0 + ac * 16 + q * 4);
  };
  auto issueB = [&](int t, int ib) {
    const int k0 = t * BKB;
#pragma unroll
    for (int p = 0; p < 8; ++p) {
      const int grow = wid * 32 + p * 4 + bro;
      const int gsrc = (lane & 7) ^ (((p & 1) * 4 + bro) & 7);
      const ushort* gp = hTB + (size_t)grow * NSEQ + k0 + bhalf * 64 + gsrc * 8;
      char* lp = lB(ib) + wid * 8192 + p * 1024;
      __builtin_amdgcn_global_load_lds(
          (const __attribute__((address_space(1))) void*)gp,
          (__attribute__((address_space(3))) void*)lp, 16, 0, 0);
    }
  };
  auto writeA = [&](int ia) {
    char* lAp = lA(ia);
    const int half = ac >> 2;
#pragma unroll
    for (int q = 0; q < 4; ++q) {
      rsum += rS[q][0] + rS[q][1] + rS[q][2] + rS[q][3];
      ushort4 u = make_ushort4(f2bf(rS[q][0]), f2bf(rS[q][1]),
                               f2bf(rS[q][2]), f2bf(rS[q][3]));
      const int gih = (((ac & 3) * 2 + (q >> 1)) ^ (arow & 7));
      *reinterpret_cast<ushort4*>(lAp + arow * 256 + half * 128 + gih * 16 +
                                  (q & 1) * 8) = u;
    }
  };
  auto mma32 = [&](const char* lAp, const char* lBp) {
    const int r16 = lane & 15;
    const int sub = lane >> 4;
#pragma unroll
    for (int kk = 0; kk < 4; ++kk) {
      const int half = kk >> 1;
      const int gih = (((kk & 1) * 4 + sub) ^ (r16 & 7));
      const int bofs = half * 128 + gih * 16;
      bf16x8 a[2], b[4];
#pragma unroll
      for (int mi = 0; mi < 2; ++mi) {
        const int row = wm * 32 + mi * 16 + r16;
        a[mi] = *reinterpret_cast<const bf16x8*>(lAp + row * 256 + bofs);
      }
#pragma unroll
      for (int ni = 0; ni < 4; ++ni) {
        const int row = wn * 64 + ni * 16 + r16;
        b[ni] = *reinterpret_cast<const bf16x8*>(lBp + row * 256 + bofs);
      }
#pragma unroll
      for (int mi = 0; mi < 2; ++mi)
#pragma unroll
        for (int ni = 0; ni < 4; ++ni)
          acc[mi][ni] = __builtin_amdgcn_mfma_f32_16x16x32_bf16(
              a[mi], b[ni], acc[mi][ni], 0, 0, 0);
    }
  };

  issueA(0);
  __builtin_amdgcn_sched_barrier(0);
  issueB(0, 0);
  __builtin_amdgcn_sched_barrier(0);
  asm volatile("s_waitcnt vmcnt(8)" ::: "memory");
  __builtin_amdgcn_sched_barrier(0);
  writeA(0);
  asm volatile("s_waitcnt vmcnt(0) lgkmcnt(0)" ::: "memory");
  __builtin_amdgcn_s_barrier();
  __builtin_amdgcn_sched_barrier(0);

  auto body = [&](int t, int cur) {
    issueA(t + 1);
    __builtin_amdgcn_sched_barrier(0);
    issueB(t + 1, cur ^ 1);
    __builtin_amdgcn_sched_barrier(0);
    __builtin_amdgcn_s_setprio(1);
    mma32(lA(cur), lB(cur));
    __builtin_amdgcn_s_setprio(0);
    asm volatile("s_waitcnt vmcnt(8)" ::: "memory");
    __builtin_amdgcn_sched_barrier(0);
    writeA(cur ^ 1);
    asm volatile("s_waitcnt vmcnt(0) lgkmcnt(0)" ::: "memory");
    __builtin_amdgcn_s_barrier();
    __builtin_amdgcn_sched_barrier(0);
  };

  for (int j = 0; j < 15; ++j) {
    body(2 * j, 0);
    body(2 * j + 1, 1);
  }
  body(30, 0);
  __builtin_amdgcn_s_setprio(1);
  mma32(lA(1), lB(1));
  __builtin_amdgcn_s_setprio(0);

  // ---------------- Epilogue: out = PReLU(tmp @ W^T + bias*rowsum) ----------------
  const float alpha = *alphaP;
  __syncthreads();

  // Phase 1: tmp (fp32 acc) -> bf16 LDS [64][264]; rowsum partials.
  ushort* lT64 = (ushort*)smem;           // 33792 B at [0, 33792)
  float* rsP = (float*)(smem + 98304);    // [64][8] partials (2 KB)
  float* rsW = (float*)(smem + 100352);   // [64] reduced
  const int TP2 = 264;
#pragma unroll
  for (int mi = 0; mi < 2; ++mi) {
    const int rbase = wm * 32 + mi * 16 + ((lane >> 4) << 2);
#pragma unroll
    for (int ni = 0; ni < 4; ++ni) {
      const int f = wn * 64 + ni * 16 + (lane & 15);
#pragma unroll
      for (int j = 0; j < 4; ++j) lT64[(rbase + j) * TP2 + f] = f2bf(acc[mi][ni][j]);
    }
  }
  rsP[arow * 8 + ac] = rsum;
  __syncthreads();
  if (tid < 64) {
    float s = 0.f;
#pragma unroll
    for (int i = 0; i < 8; ++i) s += rsP[tid * 8 + i];
    rsW[tid] = s;
  }

  // Phase 2: 4 chunks of W (64 f each): stage (linear's lwrite pattern) + GEMM.
  ushort* lW = (ushort*)(smem + 49152);   // [256][64] bf16 swz, 32 KB
  f32x4 accO[2][4];
#pragma unroll
  for (int mi = 0; mi < 2; ++mi)
#pragma unroll
    for (int ni = 0; ni < 4; ++ni) accO[mi][ni] = zero;
  const int war = tid >> 4, wac = tid & 15;
  for (int c = 0; c < 4; ++c) {
    __syncthreads();  // prior chunk's reads done before overwrite
    f32x4 rW[8];
#pragma unroll
    for (int p = 0; p < 8; ++p)
      rW[p] = *reinterpret_cast<const f32x4*>(
          W + (size_t)(war + p * 32) * FT + c * 64 + wac * 4);
#pragma unroll
    for (int p = 0; p < 8; ++p) {
      ushort4 u = make_ushort4(f2bf(rW[p][0]), f2bf(rW[p][1]),
                               f2bf(rW[p][2]), f2bf(rW[p][3]));
      *reinterpret_cast<ushort4*>((char*)lW + swz(war + p * 32, wac * 8)) = u;
    }
    __syncthreads();
    const int r16 = lane & 15;
    const int g16 = (lane >> 4) * 16;
#pragma unroll
    for (int kk = 0; kk < 2; ++kk) {
      const int kb = kk * 64 + g16;                        // byte off (B side)
      const int fo = c * 64 + kk * 32 + (lane >> 4) * 8;   // elem off (A side)
      bf16x8 a[2], b[4];
#pragma unroll
      for (int mi = 0; mi < 2; ++mi) {
        const int row = wm * 32 + mi * 16 + r16;
        a[mi] = *reinterpret_cast<const bf16x8*>(&lT64[row * TP2 + fo]);
      }
#pragma unroll
      for (int ni = 0; ni < 4; ++ni) {
        const int row = wn * 64 + ni * 16 + r16;
        b[ni] = *reinterpret_cast<const bf16x8*>((char*)lW + swz(row, kb));
      }
#pragma unroll
      for (int mi = 0; mi < 2; ++mi)
#pragma unroll
        for (int ni = 0; ni < 4; ++ni)
          accO[mi][ni] = __builtin_amdgcn_mfma_f32_16x16x32_bf16(
              a[mi], b[ni], accO[mi][ni], 0, 0, 0);
    }
  }

  // Phase 3: bias*rowsum + PReLU -> LDS overlay -> coalesced rows.
  __syncthreads();
  float* lo = (float*)smem;  // 67584 B; lT64/lW dead, rsW (at 100352) safe
  const int PITCH = 264;
#pragma unroll
  for (int mi = 0; mi < 2; ++mi) {
    const int rbase = wm * 32 + mi * 16 + ((lane >> 4) << 2);
#pragma unroll
    for (int ni = 0; ni < 4; ++ni) {
      const int o = wn * 64 + ni * 16 + (lane & 15);
      const float bo = bias[o];
#pragma unroll
      for (int j = 0; j < 4; ++j) {
        float v = accO[mi][ni][j] + bo * rsW[rbase + j];
        v = v > 0.f ? v : alpha * v;
        lo[(rbase + j) * PITCH + o] = v;
      }
    }
  }
  __syncthreads();
  float* outB = out + ((size_t)batch * NSEQ + m0) * FT;
  const int r = tid >> 3, c8 = tid & 7;
#pragma unroll
  for (int k = 0; k < 8; ++k) {
    const int g = c8 + k * 8;
    f32x4 v = *reinterpret_cast<const f32x4*>(lo + r * PITCH + g * 4);
    __builtin_nontemporal_store(v, reinterpret_cast<f32x4*>(outB + (size_t)r * FT + g * 4));
  }
}

extern "C" void kernel_launch(void* const* d_in, const int* in_sizes, int n_in,
                              void* d_out, int out_size, void* d_ws, size_t ws_size,
                              hipStream_t stream) {
  const float* seq = (const float*)d_in[0];
  const float* adj = (const float*)d_in[1];
  const float* W = (const float*)d_in[2];
  const float* bias = (const float*)d_in[3];
  const float* alpha = (const float*)d_in[4];
  float* out = (float*)d_out;
  ushort* seqT = (ushort*)d_ws;  // [4][256][4096] bf16 = 8 MB

  transpose_cast_kernel<<<256, 512, 0, stream>>>(seq, seqT);
  bmm_prelu_kernel<<<256, 512, 0, stream>>>(adj, seqT, W, bias, alpha, out);
}